// Round 3
// baseline (665.243 us; speedup 1.0000x reference)
//
#include <hip/hip_runtime.h>
#include <hip/hip_fp16.h>

// ---------------------------------------------------------------------------
// VQFFN1: out = softmax(rmsnorm(x) @ rmsnorm(w)^T) @ w
//   x: [16384,1024] fp32   w: [4096,1024] fp32   out: [16384,1024] fp32
// fp32 scores; GEMM2 plain fp16 + split-K + f32 HW atomics.
// R2: XOR-swizzled LDS (bank conflicts 3.8e7 -> 0).
// R5: S = (xh + xl) @ wh^T; shared WH tile + b-frags across both passes.
// R6: gemm1 128x256 block tile (wave 64x128, acc[4][8]).
// R7 FAILED: gemm2 split-K 4: occupancy up, MfmaUtil flat -- drain structural.
// R8: gemm2 BK 64->128: 650us. gemm1 now dominant (70us/call, MfmaUtil 43%
//     = the 2-barrier vmcnt(0)-drain ceiling; LDS-BW ruled out by arithmetic).
// R9: gemm1 -> counted-vmcnt 4-phase pipeline (T3+T4+T5): 512 thr / 8 waves,
//     BM 128 x BN 256 x BK 64, dbuf 128KB LDS, 2 stage-rounds per phase into
//     next buf, waits vmcnt(4)@PH2 / vmcnt(2)@PH4 (never 0 in main loop),
//     raw s_barrier + lgkmcnt(0) + setprio around each 16-MFMA cluster.
//     Wait derivation: issue order/iter = [B0 B1 | B2 B3 | Ah0 Ah1 | Al0 Al1];
//     PH1+PH2 need B*+Ah* (6 oldest of 8) -> vmcnt(2) at prev PH4;
//     PH3+PH4 need Al* (oldest 2 of 6 outstanding) -> vmcnt(4) at PH2.
// ---------------------------------------------------------------------------

#define D_MODEL 1024
#define D_FF    4096
#define M_ROWS  16384
#define MC      4096

typedef _Float16 half8 __attribute__((ext_vector_type(8)));
typedef _Float16 half4 __attribute__((ext_vector_type(4)));
typedef float    floatx4 __attribute__((ext_vector_type(4)));

// async global->LDS, 16B/lane; LDS dst = wave-uniform base + lane*16 (m97)
__device__ __forceinline__ void gld_lds16(const void* g, void* l) {
  __builtin_amdgcn_global_load_lds(
      (const __attribute__((address_space(1))) void*)g,
      (__attribute__((address_space(3))) void*)l, 16, 0, 0);
}

// ---------------------------------------------------------------------------
// rmsnorm (fp32 in) + hi/lo fp16 split. One wave per row of 1024.
// ---------------------------------------------------------------------------
#define MB_X (M_ROWS / 4)
#define MB_W (D_FF / 4)
__global__ __launch_bounds__(256) void rmsnorm_split_kernel(
    const float* __restrict__ X, _Float16* __restrict__ XH,
    _Float16* __restrict__ XL, const float* __restrict__ W,
    _Float16* __restrict__ WH, _Float16* __restrict__ WL) {
  const int lane = threadIdx.x & 63;
  const bool isW = blockIdx.x >= MB_X;
  const long row = (long)(isW ? blockIdx.x - MB_X : blockIdx.x) * 4 +
                   (threadIdx.x >> 6);
  const float* x = (isW ? W : X) + row * D_MODEL;
  _Float16* YH = (isW ? WH : XH) + row * D_MODEL;
  _Float16* YL = (isW ? WL : XL) + row * D_MODEL;

  float v[16];
  float ss = 0.f;
#pragma unroll
  for (int s = 0; s < 4; s++) {
    const float4 f = *(const float4*)(x + s * 256 + lane * 4);
    v[s * 4 + 0] = f.x; v[s * 4 + 1] = f.y;
    v[s * 4 + 2] = f.z; v[s * 4 + 3] = f.w;
    ss += f.x * f.x + f.y * f.y + f.z * f.z + f.w * f.w;
  }
#pragma unroll
  for (int off = 32; off >= 1; off >>= 1) ss += __shfl_xor(ss, off);
  const float inv = rsqrtf(ss * (1.0f / D_MODEL) + 1e-6f);
#pragma unroll
  for (int s = 0; s < 4; s++) {
    half4 h, l;
#pragma unroll
    for (int j = 0; j < 4; j++) {
      const float t = v[s * 4 + j] * inv;
      const _Float16 hi = (_Float16)t;
      h[j] = hi;
      l[j] = (_Float16)(t - (float)hi);
    }
    *(half4*)(YH + s * 256 + lane * 4) = h;
    *(half4*)(YL + s * 256 + lane * 4) = l;
  }
}

// ---------------------------------------------------------------------------
// transpose w [4096,1024] fp32 -> wT [1024,4096] fp16 (unnormalized, GEMM2 B)
// ---------------------------------------------------------------------------
__global__ __launch_bounds__(256) void transpose_kernel(
    const float* __restrict__ W, _Float16* __restrict__ WT) {
  __shared__ _Float16 tile[32][33];
  const int tx = threadIdx.x & 31;
  const int ty = threadIdx.x >> 5;  // 0..7
  const int d0 = blockIdx.x * 32;
  const int c0 = blockIdx.y * 32;
#pragma unroll
  for (int i = 0; i < 32; i += 8)
    tile[ty + i][tx] = (_Float16)W[(long)(c0 + ty + i) * D_MODEL + d0 + tx];
  __syncthreads();
#pragma unroll
  for (int i = 0; i < 32; i += 8)
    WT[(long)(d0 + ty + i) * D_FF + c0 + tx] = tile[tx][ty + i];
}

// ---------------------------------------------------------------------------
// GEMM1: S[4096,4096] fp32 = (xh + xl) @ wh^T over K=1024.
// R9 counted-vmcnt 4-phase pipeline. 512 threads = 8 waves (2M x 4N),
// block tile 128x256, BK=64, wave tile 64x64 (acc[4][4]).
// LDS layout per tile: [row][slot s] where slot s holds global k-slot
// s ^ (row&7) (R2 swizzle via pre-swizzled global source col).
// Staging round r = rows [r*64, r*64+64) of a tile (linear gld_lds fill);
// 8 rounds/iter: B:4, Ah:2, Al:2, issued 2 per phase into buf[(i+1)&1].
// ---------------------------------------------------------------------------
__global__ __launch_bounds__(512, 2) void gemm1_kernel(
    const _Float16* __restrict__ XH, const _Float16* __restrict__ XL,
    const _Float16* __restrict__ WH, float* __restrict__ S) {
  __shared__ _Float16 Bs[2][256 * 64];  // 64 KB
  __shared__ _Float16 Ah[2][128 * 64];  // 32 KB
  __shared__ _Float16 Al[2][128 * 64];  // 32 KB
  const int tid = threadIdx.x;
  const int lane = tid & 63;
  const int wave = tid >> 6;

  // XCD-chunked bijective swizzle (nwg = 16*32 = 512, %8 == 0)
  const int bid = blockIdx.y * 16 + blockIdx.x;
  const int swz = ((bid & 7) << 6) | (bid >> 3);
  const int bx = swz & 15, by = swz >> 4;
  const long rowBase = (long)by * 128;
  const long colBase = (long)bx * 256;

  // staging: thread t covers (row = r*64 + (t>>3), slot = t&7) of a tile
  const int srow = tid >> 3;                       // 0..63
  const int scol = ((tid & 7) ^ (srow & 7)) * 8;   // pre-swizzled source col
  const _Float16* Bg  = WH + (colBase + srow) * (long)D_MODEL + scol;
  const _Float16* Ahg = XH + (rowBase + srow) * (long)D_MODEL + scol;
  const _Float16* Alg = XL + (rowBase + srow) * (long)D_MODEL + scol;
  const int dstOff = tid * 8;  // f16 units; round r adds r*4096

  const int wr = wave >> 2, wc = wave & 3;
  const int m16 = lane & 15, q = lane >> 4, mx7 = m16 & 7;
  const int aRow = wr * 64, bRow = wc * 64;

  floatx4 acc[4][4] = {};
  half8 b0[4], b1[4], a[4];

#define RD_A4(buf, ksl)                                                        \
  _Pragma("unroll") for (int mi = 0; mi < 4; mi++) a[mi] =                     \
      *(const half8*)(&buf[(aRow + mi * 16 + m16) * 64 +                       \
                           (((ksl)*4 + q) ^ mx7) * 8]);
#define RD_B4(buf, dst, ksl)                                                   \
  _Pragma("unroll") for (int ni = 0; ni < 4; ni++) dst[ni] =                   \
      *(const half8*)(&buf[(bRow + ni * 16 + m16) * 64 +                       \
                           (((ksl)*4 + q) ^ mx7) * 8]);
#define MFMA16(BF)                                                             \
  __builtin_amdgcn_s_setprio(1);                                               \
  _Pragma("unroll") for (int mi = 0; mi < 4; mi++)                             \
  _Pragma("unroll") for (int ni = 0; ni < 4; ni++)                             \
      acc[mi][ni] = __builtin_amdgcn_mfma_f32_16x16x32_f16(                    \
          a[mi], BF[ni], acc[mi][ni], 0, 0, 0);                                \
  __builtin_amdgcn_s_setprio(0);
#define BAR() __builtin_amdgcn_s_barrier()
#define LGKM0() asm volatile("s_waitcnt lgkmcnt(0)" ::: "memory")

  // ---- prologue: stage iter-0 tiles into buf 0 ----
  {
#pragma unroll
    for (int r = 0; r < 4; r++)
      gld_lds16(Bg + (long)r * 64 * D_MODEL, &Bs[0][r * 4096 + dstOff]);
#pragma unroll
    for (int r = 0; r < 2; r++)
      gld_lds16(Ahg + (long)r * 64 * D_MODEL, &Ah[0][r * 4096 + dstOff]);
#pragma unroll
    for (int r = 0; r < 2; r++)
      gld_lds16(Alg + (long)r * 64 * D_MODEL, &Al[0][r * 4096 + dstOff]);
    asm volatile("s_waitcnt vmcnt(2)" ::: "memory");  // B+Ah landed; Al flying
    BAR();
    __builtin_amdgcn_sched_barrier(0);
  }

  for (int i = 0; i < 16; i++) {
    const int cur = i & 1, nxt = cur ^ 1;
    const long ktn = (long)(i + 1) * 64;
    const bool lastI = (i == 15);

    // ---- PH1: hi-pass k0 ---- (stage B rounds 0,1 for next iter)
    RD_B4(Bs[cur], b0, 0);
    RD_A4(Ah[cur], 0);
    if (!lastI) {
      gld_lds16(Bg + (long)0 * 64 * D_MODEL + ktn, &Bs[nxt][0 * 4096 + dstOff]);
      gld_lds16(Bg + (long)1 * 64 * D_MODEL + ktn, &Bs[nxt][1 * 4096 + dstOff]);
    }
    BAR();
    LGKM0();
    MFMA16(b0);
    BAR();

    // ---- PH2: hi-pass k1 ---- (stage B rounds 2,3; drain current Al)
    RD_B4(Bs[cur], b1, 1);
    RD_A4(Ah[cur], 1);
    if (!lastI) {
      gld_lds16(Bg + (long)2 * 64 * D_MODEL + ktn, &Bs[nxt][2 * 4096 + dstOff]);
      gld_lds16(Bg + (long)3 * 64 * D_MODEL + ktn, &Bs[nxt][3 * 4096 + dstOff]);
      asm volatile("s_waitcnt vmcnt(4)" ::: "memory");  // Al(i) landed
    } else {
      asm volatile("s_waitcnt vmcnt(0)" ::: "memory");
    }
    BAR();
    LGKM0();
    MFMA16(b1);
    BAR();
    __builtin_amdgcn_sched_barrier(0);  // PH3 Al-reads must not hoist above

    // ---- PH3: lo-pass k0 ---- (stage Ah rounds 0,1)
    RD_A4(Al[cur], 0);
    if (!lastI) {
      gld_lds16(Ahg + (long)0 * 64 * D_MODEL + ktn, &Ah[nxt][0 * 4096 + dstOff]);
      gld_lds16(Ahg + (long)1 * 64 * D_MODEL + ktn, &Ah[nxt][1 * 4096 + dstOff]);
    }
    BAR();
    LGKM0();
    MFMA16(b0);
    BAR();

    // ---- PH4: lo-pass k1 ---- (stage Al rounds 0,1; drain next B+Ah)
    RD_A4(Al[cur], 1);
    if (!lastI) {
      gld_lds16(Alg + (long)0 * 64 * D_MODEL + ktn, &Al[nxt][0 * 4096 + dstOff]);
      gld_lds16(Alg + (long)1 * 64 * D_MODEL + ktn, &Al[nxt][1 * 4096 + dstOff]);
      asm volatile("s_waitcnt vmcnt(2)" ::: "memory");  // next B+Ah landed
    }
    BAR();
    LGKM0();
    MFMA16(b1);
    BAR();
    __builtin_amdgcn_sched_barrier(0);  // next PH1 reads must not hoist above
  }
#undef RD_A4
#undef RD_B4
#undef MFMA16
#undef BAR
#undef LGKM0

  // C/D frag: col = lane&15, row = quad*4 + reg  [m89/m91 verified]
#pragma unroll
  for (int mi = 0; mi < 4; mi++)
#pragma unroll
    for (int r = 0; r < 4; r++) {
      const long rr = rowBase + wr * 64 + mi * 16 + q * 4 + r;
#pragma unroll
      for (int ni = 0; ni < 4; ni++)
        S[rr * D_FF + colBase + wc * 64 + ni * 16 + m16] = acc[mi][ni][r];
    }
}

// GEMM2: O[4096,1024] fp32 += P[4096, lda 8192] @ WT[1024,4096]^T
// 128x128 tile, BK=128 (R8), split-K=2, HW f32 atomics into pre-zeroed O.
__global__ __launch_bounds__(256, 2) void gemm2_kernel(
    const _Float16* __restrict__ P, const _Float16* __restrict__ WT,
    float* __restrict__ O) {
  constexpr int BK = 128, K = D_FF, LDA = 2 * D_FF, KSPLIT = 2048;
  __shared__ _Float16 As[128 * BK];  // 32 KB
  __shared__ _Float16 Bs[128 * BK];  // 32 KB
  const int tid = threadIdx.x;
  const int wave = tid >> 6, lane = tid & 63;

  // XCD-chunked bijective swizzle (nwg = 8*32*2 = 512, %8 == 0)
  const int bid = ((blockIdx.z * 32 + blockIdx.y) << 3) | blockIdx.x;
  const int swz = ((bid & 7) << 6) | (bid >> 3);
  const int bx = swz & 7;          // col-block   0..7
  const int by = (swz >> 3) & 31;  // row-block   0..31
  const int bz = swz >> 8;         // K-split     0..1

  const long rowBase = (long)by * 128;
  const long colBase = (long)bx * 128;
  const int k0 = bz * KSPLIT;

  // staging geometry: 1 gld_lds16 instr = 1KB = 4 rows x 256B
  const int srow4 = lane >> 4;              // 0..3
  const int slotE = (lane & 15) ^ srow4;    // even-i swizzled 16B slot
  const int slotO = slotE ^ 4;              // odd-i  (row&7 gains +4)
  const _Float16* AgE = P + (rowBase + wave * 32 + srow4) * (long)LDA + slotE * 8;
  const _Float16* AgO = P + (rowBase + wave * 32 + srow4) * (long)LDA + slotO * 8;
  const _Float16* BgE = WT + (colBase + wave * 32 + srow4) * (long)K + slotE * 8;
  const _Float16* BgO = WT + (colBase + wave * 32 + srow4) * (long)K + slotO * 8;
  _Float16* AsW = As + wave * 4096 + lane * 8;  // 32 rows/wave * 128
  _Float16* BsW = Bs + wave * 4096 + lane * 8;
  const int wr = wave >> 1, wc = wave & 1;
  const int m16 = lane & 15, q = lane >> 4;
  const int mx7 = m16 & 7;

  floatx4 acc[4][4] = {};

  for (int kt = k0; kt < k0 + KSPLIT; kt += BK) {
#pragma unroll
    for (int i = 0; i < 8; i++) {
      const _Float16* ag = (i & 1) ? AgO : AgE;
      const _Float16* bg = (i & 1) ? BgO : BgE;
      gld_lds16(ag + (long)i * 4 * LDA + kt, AsW + i * 512);
      gld_lds16(bg + (long)i * 4 * K + kt, BsW + i * 512);
    }
    __syncthreads();
#pragma unroll
    for (int ks = 0; ks < 4; ks++) {
      const int kx = ((ks * 4 + q) ^ mx7) * 8;
      half8 a[4], b[4];
#pragma unroll
      for (int mi = 0; mi < 4; mi++)
        a[mi] = *(const half8*)(&As[(wr * 64 + mi * 16 + m16) * BK + kx]);
#pragma unroll
      for (int ni = 0; ni < 4; ni++)
        b[ni] = *(const half8*)(&Bs[(wc * 64 + ni * 16 + m16) * BK + kx]);
#pragma unroll
      for (int mi = 0; mi < 4; mi++)
#pragma unroll
        for (int ni = 0; ni < 4; ni++)
          acc[mi][ni] = __builtin_amdgcn_mfma_f32_16x16x32_f16(
              a[mi], b[ni], acc[mi][ni], 0, 0, 0);
    }
    __syncthreads();
  }

#pragma unroll
  for (int mi = 0; mi < 4; mi++)
#pragma unroll
    for (int r = 0; r < 4; r++) {
      const long rr = rowBase + wr * 64 + mi * 16 + q * 4 + r;
#pragma unroll
      for (int ni = 0; ni < 4; ni++)
        unsafeAtomicAdd(&O[rr * D_MODEL + colBase + wc * 64 + ni * 16 + m16],
                        acc[mi][ni][r]);
    }
}

// ---------------------------------------------------------------------------
// softmax over rows of 4096: fp32 S in, fp16 P out in-place at row start.
// ---------------------------------------------------------------------------
__global__ __launch_bounds__(256) void softmax_kernel(float* __restrict__ S) {
  float* s = S + (long)blockIdx.x * D_FF;
  const int t = threadIdx.x;
  const int lane = t & 63, wave = t >> 6;
  __shared__ float redm[4], redl[4];

  float v[16];
  float mx = -3.4e38f;
#pragma unroll
  for (int seg = 0; seg < 4; seg++) {
    const float4 f = *(const float4*)(s + seg * 1024 + t * 4);
    v[seg * 4 + 0] = f.x; v[seg * 4 + 1] = f.y;
    v[seg * 4 + 2] = f.z; v[seg * 4 + 3] = f.w;
  }
#pragma unroll
  for (int j = 0; j < 16; j++) mx = fmaxf(mx, v[j]);
#pragma unroll
  for (int off = 32; off >= 1; off >>= 1) mx = fmaxf(mx, __shfl_xor(mx, off));
  if (lane == 0) redm[wave] = mx;
  __syncthreads();
  const float m = fmaxf(fmaxf(redm[0], redm[1]), fmaxf(redm[2], redm[3]));

  float sum = 0.f;
#pragma unroll
  for (int j = 0; j < 16; j++) {
    v[j] = __expf(v[j] - m);
    sum += v[j];
  }
#pragma unroll
  for (int off = 32; off >= 1; off >>= 1) sum += __shfl_xor(sum, off);
  if (lane == 0) redl[wave] = sum;
  __syncthreads();
  const float inv = 1.f / (redl[0] + redl[1] + redl[2] + redl[3]);

  _Float16* p = (_Float16*)s;  // all reads of this row completed above
#pragma unroll
  for (int seg = 0; seg < 4; seg++) {
    half4 h;
#pragma unroll
    for (int j = 0; j < 4; j++) h[j] = (_Float16)(v[seg * 4 + j] * inv);
    *(half4*)(p + seg * 1024 + t * 4) = h;
  }
}

// ---------------------------------------------------------------------------
extern "C" void kernel_launch(void* const* d_in, const int* in_sizes, int n_in,
                              void* d_out, int out_size, void* d_ws, size_t ws_size,
                              hipStream_t stream) {
  const float* x = (const float*)d_in[0];  // [16384,1024] fp32
  const float* w = (const float*)d_in[1];  // [4096,1024] fp32
  float* out = (float*)d_out;              // [16384,1024] fp32

  // ws layout: xh 32Mi | xl 32Mi | wh 8Mi | wl 8Mi | wT 8Mi | S 64Mi = 152Mi
  const size_t NEED = 152ull << 20;
  if (ws_size < NEED) return;

  char* ws = (char*)d_ws;
  _Float16* xh = (_Float16*)(ws);
  _Float16* xl = (_Float16*)(ws + (32ull << 20));
  _Float16* wh = (_Float16*)(ws + (64ull << 20));
  _Float16* wl = (_Float16*)(ws + (72ull << 20));  // written, unused (R5)
  _Float16* wT = (_Float16*)(ws + (80ull << 20));
  float*    S  = (float*)   (ws + (88ull << 20));

  // gemm2 accumulates via atomics -> zero d_out first (graph-capture safe)
  hipMemsetAsync(d_out, 0, (size_t)M_ROWS * D_MODEL * sizeof(float), stream);

  hipLaunchKernelGGL(rmsnorm_split_kernel, dim3(MB_X + MB_W), dim3(256), 0,
                     stream, x, xh, xl, w, wh, wl);
  hipLaunchKernelGGL(transpose_kernel, dim3(D_MODEL / 32, D_FF / 32), dim3(256),
                     0, stream, w, wT);

  for (int c = 0; c < M_ROWS / MC; c++) {
    const long ro = (long)c * MC;
    hipLaunchKernelGGL(gemm1_kernel, dim3(D_FF / 256, MC / 128), dim3(512), 0,
                       stream, xh + ro * D_MODEL, xl + ro * D_MODEL, wh, S);
    hipLaunchKernelGGL(softmax_kernel, dim3(MC), dim3(256), 0, stream, S);
    hipLaunchKernelGGL(gemm2_kernel, dim3(D_MODEL / 128, MC / 128, 2),
                       dim3(256), 0, stream, (const _Float16*)S, wT,
                       out + ro * D_MODEL);
  }
}